// Round 2
// baseline (543.862 us; speedup 1.0000x reference)
//
#include <hip/hip_runtime.h>

#define BIMG 8
#define NBOX 100000
#define NCLS 80
#define KDET 300
#define CAP  2048
#define CAPC 12                 // per-block per-class LDS staging capacity
#define TPUSH 0.9921875f        // common-path push threshold (127/128): E[cnt]=781
#define SCORE_T 0.05f
#define NELEM 8000000           // N*C per image
#define NQ    2000000           // float4s per image

typedef unsigned long long u64;
typedef unsigned u32;

// workspace layout (bytes)
#define OFF_PUSHCNT 0u              // 640*4 = 2560
#define OFF_IMGDONE 2560u           // 8*4 = 32
#define ZERO_BYTES  2592u
#define OFF_BUF     4096u           // 640*2048*8 = 10485760
#define OFF_KCNT    (4096u + 10485760u)     // 640*4
#define OFF_KSC     (OFF_KCNT + 2560u)      // 640*300*4
#define OFF_KIDX    (OFF_KSC + 768000u)     // 640*300*4

static __device__ __forceinline__ u64 mk_key(float sc, u32 n) {
  return ((u64)__float_as_uint(sc) << 32) | (u32)(~n);
}

// One radix-select step over `hist[nbins]` (single copy), executed by wave 0.
// Finds bin of the sk-th largest (counting from top), updates spfx/sk.
// Caller must __syncthreads() before and after.
static __device__ __forceinline__ void radix_step(const u32* hist, int nbins,
                                                  int width, u32* sk, u64* spfx,
                                                  u32* stot) {
  if (threadIdx.x < 64) {
    const int lane = threadIdx.x;
    const int chunk = nbins >> 6;
    u32 psum = 0;
    for (int i = 0; i < chunk; ++i) psum += hist[lane * chunk + i];
    u32 suf = psum;
#pragma unroll
    for (int off = 1; off < 64; off <<= 1) {
      u32 o = __shfl_down(suf, off);
      if (lane + off < 64) suf += o;
    }
    if (lane == 0) *stot = suf;          // lane0 suffix == total
    u32 k = *sk;
    u64 bal = __ballot(suf >= k);
    if (bal != 0ull) {
      int L = 63 - __clzll((long long)bal);
      if (lane == L) {
        u32 krem = k - (suf - psum);     // remaining within this chunk (from top)
        int bi = (L + 1) * chunk - 1;
        u32 acc = 0;
        for (;;) {
          acc += hist[bi];
          if (acc >= krem || bi == L * chunk) break;
          --bi;
        }
        *spfx = (*spfx << width) | (u32)bi;
        *sk = krem - (acc - hist[bi]);
      }
    }
  }
}

__constant__ int RSH[6] = {53, 42, 31, 20, 9, 0};
__constant__ int RWD[6] = {11, 11, 11, 11, 11, 9};

// bitonic sort 512 descending over tk[], hybrid register/shfl form.
// All 512 threads must call. Leaves sorted data in tk[] with a trailing barrier.
static __device__ __forceinline__ void bitonic512(u64* tk, int t) {
  u64 a = tk[t];
#pragma unroll
  for (int k2 = 2; k2 <= 64; k2 <<= 1) {
#pragma unroll
    for (int j = k2 >> 1; j > 0; j >>= 1) {
      u64 c2 = __shfl_xor(a, j);
      bool takeMax = (((t & k2) == 0) == ((t & j) == 0));
      u64 mx = (a > c2) ? a : c2;
      u64 mn = (a > c2) ? c2 : a;
      a = takeMax ? mx : mn;
    }
  }
#pragma unroll
  for (int k2 = 128; k2 <= 512; k2 <<= 1) {
    for (int j = k2 >> 1; j >= 64; j >>= 1) {
      tk[t] = a;
      __syncthreads();
      u64 c2 = tk[t ^ j];
      bool takeMax = (((t & k2) == 0) == ((t & j) == 0));
      u64 mx = (a > c2) ? a : c2;
      u64 mn = (a > c2) ? c2 : a;
      a = takeMax ? mx : mn;
      __syncthreads();
    }
#pragma unroll
    for (int j = 32; j > 0; j >>= 1) {
      u64 c2 = __shfl_xor(a, j);
      bool takeMax = (((t & k2) == 0) == ((t & j) == 0));
      u64 mx = (a > c2) ? a : c2;
      u64 mn = (a > c2) ? c2 : a;
      a = takeMax ? mx : mn;
    }
  }
  tk[t] = a;
  __syncthreads();
}

// ---------------- pass A: threshold push with block-local aggregation ----------------
static __device__ __forceinline__ void pushone(int c, float sc, u32 n, int b,
                                               u32* lcnt, u64* stage,
                                               u32* pushcnt, u64* buf) {
  u64 key = mk_key(sc, n);
  u32 slot = atomicAdd(&lcnt[c], 1u);
  if (slot < CAPC) {
    stage[c * CAPC + slot] = key;
  } else {    // rare LDS-staging overflow: direct global push
    u32 g = atomicAdd(&pushcnt[b * NCLS + c], 1u);
    if (g < CAP) buf[(size_t)(b * NCLS + c) * CAP + g] = key;
  }
}

__global__ __launch_bounds__(256) void histK(const float* __restrict__ cls,
                                             u32* __restrict__ pushcnt,
                                             u64* __restrict__ buf) {
  __shared__ u32 lcnt[NCLS];
  __shared__ u32 sbase[NCLS];
  __shared__ u64 stage[NCLS * CAPC];   // 7.7 KB

  const int t = threadIdx.x;
  const int b = blockIdx.y;
  for (int i = t; i < NCLS; i += 256) lcnt[i] = 0;
  __syncthreads();

  const float4* base4 = (const float4*)(cls + (size_t)b * NELEM);
  const int start = blockIdx.x * 8192;   // 245 blocks/img * 8192 float4 >= 2M

#define PROCQ(u) do { \
    float mx = fmaxf(fmaxf(v##u.x, v##u.y), fmaxf(v##u.z, v##u.w)); \
    if (mx >= TPUSH) { \
      const int e0 = q##u * 4; \
      const int c0 = e0 % NCLS; \
      const u32 n = (u32)(e0 / NCLS); \
      if (v##u.x >= TPUSH) pushone(c0 + 0, v##u.x, n, b, lcnt, stage, pushcnt, buf); \
      if (v##u.y >= TPUSH) pushone(c0 + 1, v##u.y, n, b, lcnt, stage, pushcnt, buf); \
      if (v##u.z >= TPUSH) pushone(c0 + 2, v##u.z, n, b, lcnt, stage, pushcnt, buf); \
      if (v##u.w >= TPUSH) pushone(c0 + 3, v##u.w, n, b, lcnt, stage, pushcnt, buf); \
    } } while (0)

  if (start + 8192 <= NQ) {            // full blocks: no bounds checks
    for (int it = 0; it < 4; ++it) {
      const int qb = start + it * 2048 + t;
#define LOADF(u) const int q##u = qb + (u) * 256; const float4 v##u = base4[q##u]
      LOADF(0); LOADF(1); LOADF(2); LOADF(3);
      LOADF(4); LOADF(5); LOADF(6); LOADF(7);
#undef LOADF
      PROCQ(0); PROCQ(1); PROCQ(2); PROCQ(3);
      PROCQ(4); PROCQ(5); PROCQ(6); PROCQ(7);
    }
  } else {                              // tail block: checked loads
    for (int it = 0; it < 4; ++it) {
      const int qb = start + it * 2048 + t;
#define LOADC(u) const int q##u = qb + (u) * 256; \
  const float4 v##u = (q##u < NQ) ? base4[q##u] : make_float4(0.f, 0.f, 0.f, 0.f)
      LOADC(0); LOADC(1); LOADC(2); LOADC(3);
      LOADC(4); LOADC(5); LOADC(6); LOADC(7);
#undef LOADC
      PROCQ(0); PROCQ(1); PROCQ(2); PROCQ(3);
      PROCQ(4); PROCQ(5); PROCQ(6); PROCQ(7);
    }
  }
#undef PROCQ
  __syncthreads();

  // one global atomic per (block, class) to reserve a contiguous range
  if (t < NCLS) {
    u32 cnt = min(lcnt[t], (u32)CAPC);
    sbase[t] = cnt ? atomicAdd(&pushcnt[b * NCLS + t], cnt) : 0u;
  }
  __syncthreads();
  for (int idx = t; idx < NCLS * CAPC; idx += 256) {
    const int c = idx / CAPC;
    const int k = idx - c * CAPC;
    if ((u32)k < min(lcnt[c], (u32)CAPC)) {
      u32 s = sbase[c] + (u32)k;
      if (s < CAP) buf[(size_t)(b * NCLS + c) * CAP + s] = stage[idx];
    }
  }
}

// ---------------- per (b,c): fallback (fused, rare) + radix top-300 + sort-512
// + NMS + compact; last-finishing block per image also does the global merge ------
__global__ __launch_bounds__(512) void nmsK(const float* __restrict__ boxes,
                                            const float* __restrict__ cls,
                                            const u32* __restrict__ pushcnt,
                                            u64* __restrict__ buf,
                                            u32* __restrict__ keptCnt,
                                            float* __restrict__ keptScore,
                                            u32* __restrict__ keptIdx,
                                            u32* __restrict__ imgDone,
                                            float* __restrict__ out) {
  __shared__ float bx[KDET][4];                 // 4.8 KB
  __shared__ float scl[KDET];
  __shared__ u32 nn_[KDET];
  __shared__ u64 msk[KDET][5];                  // 12 KB (aliased as hist scratch)
  __shared__ u64 tk[512];                       // 4 KB
  __shared__ u64 keptw[5];
  __shared__ u64 spfx;
  __shared__ u64 sand, sor;
  __shared__ u32 sk, stot, stcnt, smtot, smerge;
  __shared__ int msc[NCLS];
  __shared__ u32 sfpfx, sfk, sfab, sfeq, sfmode, sfbcnt;

  const int t = threadIdx.x;
  const int bc = blockIdx.x;
  const int b = bc / NCLS;
  u64* bufp = buf + (size_t)bc * CAP;
  u32* hist = (u32*)&msk[0][0];   // 2048-bin scratch, dead before masks are built

  if (t == 0) { spfx = 0ull; sk = KDET; stcnt = 0u; sfmode = 0u; sfbcnt = 0u; }

  // ---- fused exact fallback (never taken on common inputs) ----
  u32 realcnt = pushcnt[bc];
  const bool dofb = !(realcnt >= (u32)KDET && realcnt <= (u32)CAP);
  if (dofb) {
    const int c = bc % NCLS;
    const float* col = cls + (size_t)b * NELEM + c;
    // MSD radix-select of the 300th-largest score-bits
    for (int r = 0; r < 3; ++r) {
      const int shift = (r == 0) ? 21 : (r == 1) ? 10 : 0;
      const int nbins = (r == 2) ? 1024 : 2048;
      for (int i = t; i < nbins; i += 512) hist[i] = 0;
      __syncthreads();
      for (int n = t; n < NBOX; n += 512) {
        float sc = col[(size_t)n * NCLS];
        if (sc > SCORE_T) {
          u32 u = __float_as_uint(sc);
          bool ok = (r == 0) || (r == 1 ? ((u >> 21) == (sfpfx >> 21))
                                        : ((u >> 10) == (sfpfx >> 10)));
          if (ok) atomicAdd(&hist[(u >> shift) & (u32)(nbins - 1)], 1u);
        }
      }
      __syncthreads();
      if (t == 0) {
        if (r == 0) {
          u32 s = 0;
          for (int i = 0; i < nbins; ++i) s += hist[i];
          if (s < KDET) sfmode = 1u;   // fewer than 300 candidates: push all
        }
        if (sfmode == 0u) {
          u32 kk2 = (r == 0) ? (u32)KDET : sfk;
          u32 acc = 0;
          int bi = nbins - 1;
          for (; bi >= 0; --bi) {
            if (acc + hist[bi] >= kk2) break;
            acc += hist[bi];
          }
          sfk = kk2 - acc;
          sfpfx = ((r == 0) ? 0u : sfpfx) | ((u32)bi << shift);
          if (r == 2) { sfeq = hist[bi]; sfab = KDET - sfk; }
        }
      }
      __syncthreads();
      if (sfmode == 1u) break;
    }

    if (sfmode == 1u) {
      for (int n = t; n < NBOX; n += 512) {
        float sc = col[(size_t)n * NCLS];
        if (sc > SCORE_T) {
          u32 g = atomicAdd(&sfbcnt, 1u);
          if (g < CAP) bufp[g] = mk_key(sc, (u32)n);
        }
      }
    } else {
      const u32 ustar = sfpfx;
      const u32 m = sfab, e = sfeq;
      if (m + e <= CAP) {
        for (int n = t; n < NBOX; n += 512) {
          float sc = col[(size_t)n * NCLS];
          if (sc > SCORE_T && __float_as_uint(sc) >= ustar) {
            u32 g = atomicAdd(&sfbcnt, 1u);
            if (g < CAP) bufp[g] = mk_key(sc, (u32)n);
          }
        }
      } else {
        for (int n = t; n < NBOX; n += 512) {
          float sc = col[(size_t)n * NCLS];
          if (sc > SCORE_T && __float_as_uint(sc) > ustar) {
            u32 g = atomicAdd(&sfbcnt, 1u);
            if (g < CAP) bufp[g] = mk_key(sc, (u32)n);
          }
        }
        __syncthreads();
        if (t == 0) {
          u32 room = CAP - m, got = 0;
          for (int n = 0; n < NBOX && got < room; ++n) {
            float sc = col[(size_t)n * NCLS];
            if (sc > SCORE_T && __float_as_uint(sc) == ustar) {
              u32 g = atomicAdd(&sfbcnt, 1u);
              if (g < CAP) bufp[g] = mk_key(sc, (u32)n);
              ++got;
            }
          }
        }
      }
    }
    __threadfence_block();
    __syncthreads();
    realcnt = sfbcnt;
  }
  const int cnt = min((int)realcnt, CAP);

  u64 kk[4];
#pragma unroll
  for (int u = 0; u < 4; ++u) {
    int i = t + u * 512;
    u64 v = 0ull;
    if (i < cnt)
      v = dofb ? *((volatile const u64*)(bufp + i)) : bufp[i];   // L1-bypass on rare path
    kk[u] = v;
  }

  const bool normal = (cnt > KDET);   // block-uniform
  if (normal) {
    // block AND/OR of keys: bit groups with AND==OR are constant -> skip pass
    if (t == 0) { sand = ~0ull; sor = 0ull; }
    __syncthreads();
    {
      u64 ka = ~0ull, ko = 0ull;
#pragma unroll
      for (int u = 0; u < 4; ++u) {
        u64 key = kk[u];
        if (key) { ka &= key; ko |= key; }
      }
#pragma unroll
      for (int off = 32; off > 0; off >>= 1) {
        ka &= __shfl_xor(ka, off);
        ko |= __shfl_xor(ko, off);
      }
      if ((t & 63) == 0) {
        atomicAnd((unsigned long long*)&sand, (unsigned long long)ka);
        atomicOr((unsigned long long*)&sor, (unsigned long long)ko);
      }
    }
    __syncthreads();
    const u64 kand = sand, kor = sor;
    for (int p = 0; p < 6; ++p) {
      const int nb = (p == 5) ? 512 : 2048;
      const u32 mask = (u32)(nb - 1);
      const u32 ba = (u32)(kand >> RSH[p]) & mask;
      const u32 bo = (u32)(kor >> RSH[p]) & mask;
      if (ba == bo) {                      // constant bits: free prefix extension
        if (t == 0) spfx = (spfx << RWD[p]) | (u64)ba;
        __syncthreads();
        continue;
      }
      for (int i = t; i < nb; i += 512) hist[i] = 0;
      __syncthreads();
      const u64 pfx = spfx;
#pragma unroll
      for (int u = 0; u < 4; ++u) {
        u64 key = kk[u];
        if (!key) continue;
        if (p > 0 && (key >> RSH[p - 1]) != pfx) continue;
        atomicAdd(&hist[(u32)(key >> RSH[p]) & mask], 1u);
      }
      __syncthreads();
      radix_step(hist, nb, RWD[p], &sk, &spfx, &stot);
      __syncthreads();
    }
  } else {
    __syncthreads();
  }
  const u64 thr = normal ? spfx : 1ull;   // exact 300th-largest key (keys unique)

  tk[t] = 0ull;
  __syncthreads();
#pragma unroll
  for (int u = 0; u < 4; ++u) {
    u64 key = kk[u];
    if (key >= thr && key != 0ull) {
      u32 pos = atomicAdd(&stcnt, 1u);
      if (pos < 512) tk[pos] = key;
    }
  }
  __syncthreads();

  bitonic512(tk, t);

  const int M = min((int)stcnt, KDET);
  for (int i = t; i < M; i += 512) {
    u64 key = tk[i];
    u32 n = ~(u32)key;
    scl[i] = __uint_as_float((u32)(key >> 32));
    nn_[i] = n;
    const float4 bv = *(const float4*)(boxes + ((size_t)b * NBOX + n) * 4);
    bx[i][0] = bv.x; bx[i][1] = bv.y; bx[i][2] = bv.z; bx[i][3] = bv.w;
  }
  __syncthreads();

  // suppression masks: bit j of msk[i] set iff IoU(box_i, box_j) >= 0.5, j < i
  for (int i = t; i < M; i += 512) {
    float x1 = bx[i][0], y1 = bx[i][1], x2 = bx[i][2], y2 = bx[i][3];
    float a1 = (x2 - x1) * (y2 - y1);
    u64 m0 = 0, m1 = 0, m2 = 0, m3 = 0, m4 = 0;
    for (int j = 0; j < i; ++j) {
      float lx = fmaxf(x1, bx[j][0]);
      float ly = fmaxf(y1, bx[j][1]);
      float rx = fminf(x2, bx[j][2]);
      float ry = fminf(y2, bx[j][3]);
      float iw = fmaxf(rx - lx, 0.0f), ih = fmaxf(ry - ly, 0.0f);
      float inter = iw * ih;
      float a2 = (bx[j][2] - bx[j][0]) * (bx[j][3] - bx[j][1]);
      float uni = fmaxf(a1 + a2 - inter, 1e-7f);
      float iou = inter / uni;   // true IEEE division: matches reference rounding
      if (iou >= 0.5f) {
        u64 bit = 1ull << (j & 63);
        switch (j >> 6) {
          case 0: m0 |= bit; break;
          case 1: m1 |= bit; break;
          case 2: m2 |= bit; break;
          case 3: m3 |= bit; break;
          default: m4 |= bit; break;
        }
      }
    }
    msk[i][0] = m0; msk[i][1] = m1; msk[i][2] = m2; msk[i][3] = m3; msk[i][4] = m4;
  }
  __syncthreads();

  // ---- wave-parallel greedy NMS scan (monotone-ballot) ----
  if (t < 64) {
    u64 kwv[5];
#pragma unroll
    for (int w = 0; w < 5; ++w) {
      const int i = w * 64 + t;
      bool pb = (i < M);
      u64 mown = 0ull;
      if (pb) {
#pragma unroll
        for (int w2 = 0; w2 < 5; ++w2)
          if (w2 < w && (msk[i][w2] & kwv[w2])) pb = false;
        mown = msk[i][w];
      }
      u64 kv = 0ull;
      for (;;) {
        u64 bal = __ballot(pb && ((mown & kv) == 0ull));
        if (!bal) break;
        int p = __ffsll((unsigned long long)bal) - 1;
        kv |= 1ull << p;
        if (t == p) pb = false;
      }
      kwv[w] = kv;
      if (t == 0) keptw[w] = kv;
    }
  }
  __syncthreads();

  for (int i = t; i < M; i += 512) {
    if ((keptw[i >> 6] >> (i & 63)) & 1ull) {
      int rank = 0;
      for (int w = 0; w < (i >> 6); ++w) rank += __popcll(keptw[w]);
      rank += __popcll(keptw[i >> 6] & ((1ull << (i & 63)) - 1ull));
      keptScore[(size_t)bc * KDET + rank] = scl[i];
      keptIdx[(size_t)bc * KDET + rank] = nn_[i];
    }
  }
  if (t == 0) {
    int tot = 0;
    for (int w = 0; w < 5; ++w) tot += __popcll(keptw[w]);
    keptCnt[bc] = (u32)tot;
  }
  __syncthreads();   // all class outputs issued before the election

  // ---------- fused per-image merge: 80th finisher of each image runs it ----------
  if (t == 0) {
    __threadfence();                     // publish this block's kept* writes
    u32 done = atomicAdd(&imgDone[b], 1u);
    smerge = (done == NCLS - 1) ? 1u : 0u;
  }
  __syncthreads();
  if (!smerge) return;
  __threadfence();                       // acquire: other blocks' kept* now visible

  if (t == 0) { spfx = 0ull; sk = KDET; stcnt = 0u; smtot = 0u; sand = ~0ull; sor = 0ull; }
  if (t < NCLS) msc[t] = min((int)keptCnt[b * NCLS + t], KDET);
  __syncthreads();

  const float* ksc = keptScore + (size_t)b * NCLS * KDET;
  // key reconstruction: (score_bits<<32)|~idx, 0 = invalid
#define MKEY(idx, key) do { \
    int c_ = (idx) / KDET, r_ = (idx) - c_ * KDET; \
    key = (r_ < msc[c_]) ? ((u64)__float_as_uint(ksc[idx]) << 32) | (u32)(~(u32)(idx)) \
                         : 0ull; \
  } while (0)

  {  // AND/OR + total count
    u64 ka = ~0ull, ko = 0ull;
    u32 mycnt = 0;
    for (int idx = t; idx < NCLS * KDET; idx += 512) {
      u64 key; MKEY(idx, key);
      if (key) { ka &= key; ko |= key; ++mycnt; }
    }
#pragma unroll
    for (int off = 32; off > 0; off >>= 1) {
      ka &= __shfl_xor(ka, off);
      ko |= __shfl_xor(ko, off);
      mycnt += __shfl_xor(mycnt, off);
    }
    if ((t & 63) == 0) {
      atomicAnd((unsigned long long*)&sand, (unsigned long long)ka);
      atomicOr((unsigned long long*)&sor, (unsigned long long)ko);
      atomicAdd(&smtot, mycnt);
    }
  }
  __syncthreads();

  const bool mnormal = ((int)smtot > KDET);
  if (mnormal) {
    const u64 kand = sand, kor = sor;
    for (int p = 0; p < 6; ++p) {
      const int nb = (p == 5) ? 512 : 2048;
      const u32 mask = (u32)(nb - 1);
      const u32 ba = (u32)(kand >> RSH[p]) & mask;
      const u32 bo = (u32)(kor >> RSH[p]) & mask;
      if (ba == bo) {
        if (t == 0) spfx = (spfx << RWD[p]) | (u64)ba;
        __syncthreads();
        continue;
      }
      for (int i = t; i < nb; i += 512) hist[i] = 0;
      __syncthreads();
      const u64 pfx = spfx;
      for (int idx = t; idx < NCLS * KDET; idx += 512) {
        u64 key; MKEY(idx, key);
        if (!key) continue;
        if (p > 0 && (key >> RSH[p - 1]) != pfx) continue;
        atomicAdd(&hist[(u32)(key >> RSH[p]) & mask], 1u);
      }
      __syncthreads();
      radix_step(hist, nb, RWD[p], &sk, &spfx, &stot);
      __syncthreads();
    }
  }
  const u64 mthr = mnormal ? spfx : 1ull;

  tk[t] = 0ull;
  __syncthreads();
  for (int idx = t; idx < NCLS * KDET; idx += 512) {
    u64 key; MKEY(idx, key);
    if (key >= mthr && key != 0ull) {
      u32 pos = atomicAdd(&stcnt, 1u);
      if (pos < 512) tk[pos] = key;
    }
  }
  __syncthreads();
#undef MKEY

  bitonic512(tk, t);

  // outputs: boxes [B,K,4] | scores [B,K] | labels [B,K] (as float)
  if (t < KDET) {
    float* ob = out + ((size_t)b * KDET + t) * 4;
    float* os = out + (size_t)BIMG * KDET * 4;
    float* ol = os + (size_t)BIMG * KDET;
    u64 key = tk[t];
    if (key == 0ull) {
      *(float4*)ob = make_float4(-1.f, -1.f, -1.f, -1.f);
      os[(size_t)b * KDET + t] = -1.f;
      ol[(size_t)b * KDET + t] = -1.f;
    } else {
      u32 fi = ~(u32)key;
      int c = fi / KDET, r = fi - c * KDET;
      u32 n = keptIdx[((size_t)b * NCLS + c) * KDET + r];
      *(float4*)ob = *(const float4*)(boxes + ((size_t)b * NBOX + n) * 4);
      os[(size_t)b * KDET + t] = __uint_as_float((u32)(key >> 32));
      ol[(size_t)b * KDET + t] = (float)c;
    }
  }
}

extern "C" void kernel_launch(void* const* d_in, const int* in_sizes, int n_in,
                              void* d_out, int out_size, void* d_ws, size_t ws_size,
                              hipStream_t stream) {
  const float* boxes = (const float*)d_in[0];
  const float* cls = (const float*)d_in[1];
  float* out = (float*)d_out;
  char* ws = (char*)d_ws;

  u32* pushcnt = (u32*)(ws + OFF_PUSHCNT);
  u32* imgDone = (u32*)(ws + OFF_IMGDONE);
  u64* buf = (u64*)(ws + OFF_BUF);
  u32* keptCnt = (u32*)(ws + OFF_KCNT);
  float* keptScore = (float*)(ws + OFF_KSC);
  u32* keptIdx = (u32*)(ws + OFF_KIDX);

  (void)hipMemsetAsync(ws + OFF_PUSHCNT, 0, ZERO_BYTES, stream);

  histK<<<dim3(245, BIMG), 256, 0, stream>>>(cls, pushcnt, buf);
  nmsK<<<BIMG * NCLS, 512, 0, stream>>>(boxes, cls, pushcnt, buf, keptCnt,
                                        keptScore, keptIdx, imgDone, out);
}

// Round 3
// 523.006 us; speedup vs baseline: 1.0399x; 1.0399x over previous
//
#include <hip/hip_runtime.h>

#define BIMG 8
#define NBOX 100000
#define NCLS 80
#define KDET 300
#define CAP  2048
#define CAPC 12                 // per-block per-class LDS staging capacity
#define TPUSH 0.9921875f        // common-path push threshold (127/128): E[cnt]=781
#define SCORE_T 0.05f
#define NELEM 8000000           // N*C per image
#define NQ    2000000           // float4s per image

typedef unsigned long long u64;
typedef unsigned u32;

// workspace layout (bytes)
#define OFF_PUSHCNT 0u              // 640*4 = 2560
#define ZERO_BYTES  2560u
#define OFF_BUF     4096u           // 640*2048*8 = 10485760
#define OFF_KCNT    (4096u + 10485760u)     // 640*4
#define OFF_KSC     (OFF_KCNT + 2560u)      // 640*300*4
#define OFF_KIDX    (OFF_KSC + 768000u)     // 640*300*4

static __device__ __forceinline__ u64 mk_key(float sc, u32 n) {
  return ((u64)__float_as_uint(sc) << 32) | (u32)(~n);
}

// One radix-select step over `hist[nbins]` (single copy), executed by wave 0.
// Finds bin of the sk-th largest (from top), updates spfx/sk. Writes
// ssel = #keys in current subset with digit >= chosen bin (for early-exit).
// Caller must __syncthreads() before and after.
static __device__ __forceinline__ void radix_step(const u32* hist, int nbins,
                                                  int width, u32* sk, u64* spfx,
                                                  u32* ssel) {
  if (threadIdx.x < 64) {
    const int lane = threadIdx.x;
    const int chunk = nbins >> 6;
    u32 psum = 0;
    for (int i = 0; i < chunk; ++i) psum += hist[lane * chunk + i];
    u32 suf = psum;
#pragma unroll
    for (int off = 1; off < 64; off <<= 1) {
      u32 o = __shfl_down(suf, off);
      if (lane + off < 64) suf += o;
    }
    u32 k = *sk;
    u64 bal = __ballot(suf >= k);
    if (bal != 0ull) {
      int L = 63 - __clzll((long long)bal);
      if (lane == L) {
        u32 krem = k - (suf - psum);     // remaining within this chunk (from top)
        int bi = (L + 1) * chunk - 1;
        u32 acc = 0;
        for (;;) {
          acc += hist[bi];
          if (acc >= krem || bi == L * chunk) break;
          --bi;
        }
        *spfx = (*spfx << width) | (u32)bi;
        *sk = krem - (acc - hist[bi]);
        *ssel = (suf - psum) + acc;      // keys with digit >= bi in subset
      }
    }
  }
}

__constant__ int RSH[6] = {53, 42, 31, 20, 9, 0};
__constant__ int RWD[6] = {11, 11, 11, 11, 11, 9};

// bitonic sort 512 descending over tk[], hybrid register/shfl form.
// All 512 threads must call. Leaves sorted data in tk[] with a trailing barrier.
static __device__ __forceinline__ void bitonic512(u64* tk, int t) {
  u64 a = tk[t];
#pragma unroll
  for (int k2 = 2; k2 <= 64; k2 <<= 1) {
#pragma unroll
    for (int j = k2 >> 1; j > 0; j >>= 1) {
      u64 c2 = __shfl_xor(a, j);
      bool takeMax = (((t & k2) == 0) == ((t & j) == 0));
      u64 mx = (a > c2) ? a : c2;
      u64 mn = (a > c2) ? c2 : a;
      a = takeMax ? mx : mn;
    }
  }
#pragma unroll
  for (int k2 = 128; k2 <= 512; k2 <<= 1) {
    for (int j = k2 >> 1; j >= 64; j >>= 1) {
      tk[t] = a;
      __syncthreads();
      u64 c2 = tk[t ^ j];
      bool takeMax = (((t & k2) == 0) == ((t & j) == 0));
      u64 mx = (a > c2) ? a : c2;
      u64 mn = (a > c2) ? c2 : a;
      a = takeMax ? mx : mn;
      __syncthreads();
    }
#pragma unroll
    for (int j = 32; j > 0; j >>= 1) {
      u64 c2 = __shfl_xor(a, j);
      bool takeMax = (((t & k2) == 0) == ((t & j) == 0));
      u64 mx = (a > c2) ? a : c2;
      u64 mn = (a > c2) ? c2 : a;
      a = takeMax ? mx : mn;
    }
  }
  tk[t] = a;
  __syncthreads();
}

// ---------------- pass A: threshold push with block-local aggregation ----------------
static __device__ __forceinline__ void pushone(int c, float sc, u32 n, int b,
                                               u32* lcnt, u64* stage,
                                               u32* pushcnt, u64* buf) {
  u64 key = mk_key(sc, n);
  u32 slot = atomicAdd(&lcnt[c], 1u);
  if (slot < CAPC) {
    stage[c * CAPC + slot] = key;
  } else {    // rare LDS-staging overflow: direct global push
    u32 g = atomicAdd(&pushcnt[b * NCLS + c], 1u);
    if (g < CAP) buf[(size_t)(b * NCLS + c) * CAP + g] = key;
  }
}

__global__ __launch_bounds__(256) void histK(const float* __restrict__ cls,
                                             u32* __restrict__ pushcnt,
                                             u64* __restrict__ buf) {
  __shared__ u32 lcnt[NCLS];
  __shared__ u32 sbase[NCLS];
  __shared__ u64 stage[NCLS * CAPC];   // 7.7 KB

  const int t = threadIdx.x;
  const int b = blockIdx.y;
  for (int i = t; i < NCLS; i += 256) lcnt[i] = 0;
  __syncthreads();

  const float4* base4 = (const float4*)(cls + (size_t)b * NELEM);
  const int start = blockIdx.x * 8192;   // 245 blocks/img * 8192 float4 >= 2M

#define PROCQ(u) do { \
    float mx = fmaxf(fmaxf(v##u.x, v##u.y), fmaxf(v##u.z, v##u.w)); \
    if (mx >= TPUSH) { \
      const int e0 = q##u * 4; \
      const int c0 = e0 % NCLS; \
      const u32 n = (u32)(e0 / NCLS); \
      if (v##u.x >= TPUSH) pushone(c0 + 0, v##u.x, n, b, lcnt, stage, pushcnt, buf); \
      if (v##u.y >= TPUSH) pushone(c0 + 1, v##u.y, n, b, lcnt, stage, pushcnt, buf); \
      if (v##u.z >= TPUSH) pushone(c0 + 2, v##u.z, n, b, lcnt, stage, pushcnt, buf); \
      if (v##u.w >= TPUSH) pushone(c0 + 3, v##u.w, n, b, lcnt, stage, pushcnt, buf); \
    } } while (0)

  if (start + 8192 <= NQ) {            // full blocks: no bounds checks
    for (int it = 0; it < 4; ++it) {
      const int qb = start + it * 2048 + t;
#define LOADF(u) const int q##u = qb + (u) * 256; const float4 v##u = base4[q##u]
      LOADF(0); LOADF(1); LOADF(2); LOADF(3);
      LOADF(4); LOADF(5); LOADF(6); LOADF(7);
#undef LOADF
      PROCQ(0); PROCQ(1); PROCQ(2); PROCQ(3);
      PROCQ(4); PROCQ(5); PROCQ(6); PROCQ(7);
    }
  } else {                              // tail block: checked loads
    for (int it = 0; it < 4; ++it) {
      const int qb = start + it * 2048 + t;
#define LOADC(u) const int q##u = qb + (u) * 256; \
  const float4 v##u = (q##u < NQ) ? base4[q##u] : make_float4(0.f, 0.f, 0.f, 0.f)
      LOADC(0); LOADC(1); LOADC(2); LOADC(3);
      LOADC(4); LOADC(5); LOADC(6); LOADC(7);
#undef LOADC
      PROCQ(0); PROCQ(1); PROCQ(2); PROCQ(3);
      PROCQ(4); PROCQ(5); PROCQ(6); PROCQ(7);
    }
  }
#undef PROCQ
  __syncthreads();

  // one global atomic per (block, class) to reserve a contiguous range
  if (t < NCLS) {
    u32 cnt = min(lcnt[t], (u32)CAPC);
    sbase[t] = cnt ? atomicAdd(&pushcnt[b * NCLS + t], cnt) : 0u;
  }
  __syncthreads();
  for (int idx = t; idx < NCLS * CAPC; idx += 256) {
    const int c = idx / CAPC;
    const int k = idx - c * CAPC;
    if ((u32)k < min(lcnt[c], (u32)CAPC)) {
      u32 s = sbase[c] + (u32)k;
      if (s < CAP) buf[(size_t)(b * NCLS + c) * CAP + s] = stage[idx];
    }
  }
}

// ---------------- per (b,c): fallback (fused, rare) + early-term radix select
// + sort-512 + NMS + compact ----------------
__global__ __launch_bounds__(512) void nmsK(const float* __restrict__ boxes,
                                            const float* __restrict__ cls,
                                            const u32* __restrict__ pushcnt,
                                            u64* __restrict__ buf,
                                            u32* __restrict__ keptCnt,
                                            float* __restrict__ keptScore,
                                            u32* __restrict__ keptIdx) {
  __shared__ float bx[KDET][4];                 // 4.8 KB
  __shared__ float scl[KDET];
  __shared__ u32 nn_[KDET];
  __shared__ u64 msk[KDET][5];                  // 12 KB (aliased as hist scratch)
  __shared__ u64 tk[512];                       // 4 KB
  __shared__ u64 keptw[5];
  __shared__ u64 spfx;
  __shared__ u64 sand, sor;
  __shared__ u32 sk, ssel, stcnt;
  __shared__ u32 sfpfx, sfk, sfab, sfeq, sfmode, sfbcnt;

  const int t = threadIdx.x;
  const int bc = blockIdx.x;
  const int b = bc / NCLS;
  u64* bufp = buf + (size_t)bc * CAP;
  u32* hist = (u32*)&msk[0][0];   // 2048-bin scratch, dead before masks are built

  if (t == 0) { spfx = 0ull; sk = KDET; stcnt = 0u; sfmode = 0u; sfbcnt = 0u; }

  // ---- fused exact fallback (never taken on common inputs) ----
  u32 realcnt = pushcnt[bc];
  const bool dofb = !(realcnt >= (u32)KDET && realcnt <= (u32)CAP);
  if (dofb) {
    const int c = bc % NCLS;
    const float* col = cls + (size_t)b * NELEM + c;
    // MSD radix-select of the 300th-largest score-bits
    for (int r = 0; r < 3; ++r) {
      const int shift = (r == 0) ? 21 : (r == 1) ? 10 : 0;
      const int nbins = (r == 2) ? 1024 : 2048;
      for (int i = t; i < nbins; i += 512) hist[i] = 0;
      __syncthreads();
      for (int n = t; n < NBOX; n += 512) {
        float sc = col[(size_t)n * NCLS];
        if (sc > SCORE_T) {
          u32 u = __float_as_uint(sc);
          bool ok = (r == 0) || (r == 1 ? ((u >> 21) == (sfpfx >> 21))
                                        : ((u >> 10) == (sfpfx >> 10)));
          if (ok) atomicAdd(&hist[(u >> shift) & (u32)(nbins - 1)], 1u);
        }
      }
      __syncthreads();
      if (t == 0) {
        if (r == 0) {
          u32 s = 0;
          for (int i = 0; i < nbins; ++i) s += hist[i];
          if (s < KDET) sfmode = 1u;   // fewer than 300 candidates: push all
        }
        if (sfmode == 0u) {
          u32 kk2 = (r == 0) ? (u32)KDET : sfk;
          u32 acc = 0;
          int bi = nbins - 1;
          for (; bi >= 0; --bi) {
            if (acc + hist[bi] >= kk2) break;
            acc += hist[bi];
          }
          sfk = kk2 - acc;
          sfpfx = ((r == 0) ? 0u : sfpfx) | ((u32)bi << shift);
          if (r == 2) { sfeq = hist[bi]; sfab = KDET - sfk; }
        }
      }
      __syncthreads();
      if (sfmode == 1u) break;
    }

    if (sfmode == 1u) {
      for (int n = t; n < NBOX; n += 512) {
        float sc = col[(size_t)n * NCLS];
        if (sc > SCORE_T) {
          u32 g = atomicAdd(&sfbcnt, 1u);
          if (g < CAP) bufp[g] = mk_key(sc, (u32)n);
        }
      }
    } else {
      const u32 ustar = sfpfx;
      const u32 m = sfab, e = sfeq;
      if (m + e <= CAP) {
        for (int n = t; n < NBOX; n += 512) {
          float sc = col[(size_t)n * NCLS];
          if (sc > SCORE_T && __float_as_uint(sc) >= ustar) {
            u32 g = atomicAdd(&sfbcnt, 1u);
            if (g < CAP) bufp[g] = mk_key(sc, (u32)n);
          }
        }
      } else {
        for (int n = t; n < NBOX; n += 512) {
          float sc = col[(size_t)n * NCLS];
          if (sc > SCORE_T && __float_as_uint(sc) > ustar) {
            u32 g = atomicAdd(&sfbcnt, 1u);
            if (g < CAP) bufp[g] = mk_key(sc, (u32)n);
          }
        }
        __syncthreads();
        if (t == 0) {
          u32 room = CAP - m, got = 0;
          for (int n = 0; n < NBOX && got < room; ++n) {
            float sc = col[(size_t)n * NCLS];
            if (sc > SCORE_T && __float_as_uint(sc) == ustar) {
              u32 g = atomicAdd(&sfbcnt, 1u);
              if (g < CAP) bufp[g] = mk_key(sc, (u32)n);
              ++got;
            }
          }
        }
      }
    }
    __threadfence_block();
    __syncthreads();
    realcnt = sfbcnt;
  }
  const int cnt = min((int)realcnt, CAP);

  u64 kk[4];
#pragma unroll
  for (int u = 0; u < 4; ++u) {
    int i = t + u * 512;
    u64 v = 0ull;
    if (i < cnt)
      v = dofb ? *((volatile const u64*)(bufp + i)) : bufp[i];   // L1-bypass on rare path
    kk[u] = v;
  }

  const bool normal = (cnt > KDET);   // block-uniform
  int eshift = 0;
  u64 ethr = 1ull;                    // !normal: take every nonzero key
  if (normal) {
    // block AND/OR of keys: digit groups with AND==OR are constant -> skip pass
    if (t == 0) { sand = ~0ull; sor = 0ull; }
    __syncthreads();
    {
      u64 ka = ~0ull, ko = 0ull;
#pragma unroll
      for (int u = 0; u < 4; ++u) {
        u64 key = kk[u];
        if (key) { ka &= key; ko |= key; }
      }
#pragma unroll
      for (int off = 32; off > 0; off >>= 1) {
        ka &= __shfl_xor(ka, off);
        ko |= __shfl_xor(ko, off);
      }
      if ((t & 63) == 0) {
        atomicAnd((unsigned long long*)&sand, (unsigned long long)ka);
        atomicOr((unsigned long long*)&sor, (unsigned long long)ko);
      }
    }
    __syncthreads();
    const u64 kand = sand, kor = sor;
    for (int p = 0; p < 6; ++p) {
      const int nb = (p == 5) ? 512 : 2048;
      const u32 mask = (u32)(nb - 1);
      const u32 ba = (u32)(kand >> RSH[p]) & mask;
      const u32 bo = (u32)(kor >> RSH[p]) & mask;
      if (ba == bo) {                      // constant digit: free prefix extension
        if (t == 0) spfx = (spfx << RWD[p]) | (u64)ba;
        __syncthreads();
        continue;
      }
      for (int i = t; i < nb; i += 512) hist[i] = 0;
      __syncthreads();
      const u64 pfx = spfx;
      const u32 skPrev = sk;
#pragma unroll
      for (int u = 0; u < 4; ++u) {
        u64 key = kk[u];
        if (!key) continue;
        if (p > 0 && (key >> RSH[p - 1]) != pfx) continue;
        atomicAdd(&hist[(u32)(key >> RSH[p]) & mask], 1u);
      }
      __syncthreads();
      radix_step(hist, nb, RWD[p], &sk, &spfx, &ssel);
      __syncthreads();
      // keys >= (prefix|bin) = (taken above subset) + (digit >= bin within subset)
      if ((u32)KDET - skPrev + ssel <= 512u) { eshift = RSH[p]; break; }
    }
    ethr = spfx;   // threshold at granularity RSH[eshift-pass]; superset fits 512
  }

  tk[t] = 0ull;
  __syncthreads();
  {
    const int lane = t & 63;
    const u64 lmlt = (1ull << lane) - 1ull;
#pragma unroll
    for (int u = 0; u < 4; ++u) {
      u64 key = kk[u];
      bool q = (key != 0ull) && ((key >> eshift) >= ethr);
      u64 bal = __ballot(q);
      u32 nw = (u32)__popcll(bal);
      if (nw) {
        u32 base = 0;
        if (lane == 0) base = atomicAdd(&stcnt, nw);
        base = __shfl(base, 0);
        if (q) {
          u32 pos = base + (u32)__popcll(bal & lmlt);
          if (pos < 512) tk[pos] = key;
        }
      }
    }
  }
  __syncthreads();

  bitonic512(tk, t);

  const int M = min((int)stcnt, KDET);
  for (int i = t; i < M; i += 512) {
    u64 key = tk[i];
    u32 n = ~(u32)key;
    scl[i] = __uint_as_float((u32)(key >> 32));
    nn_[i] = n;
    const float4 bv = *(const float4*)(boxes + ((size_t)b * NBOX + n) * 4);
    bx[i][0] = bv.x; bx[i][1] = bv.y; bx[i][2] = bv.z; bx[i][3] = bv.w;
  }
  __syncthreads();

  // suppression masks, task-split: task = (row i, 64-col word w), 1500 tasks
  for (int tau = t; tau < KDET * 5; tau += 512) {
    const int i = tau / 5;
    const int w = tau - i * 5;
    u64 m = 0ull;
    const int jb = w << 6;
    if (i < M && jb < i) {
      const int je = min(i, jb + 64);
      const float x1 = bx[i][0], y1 = bx[i][1], x2 = bx[i][2], y2 = bx[i][3];
      const float a1 = (x2 - x1) * (y2 - y1);
      for (int j = jb; j < je; ++j) {
        float lx = fmaxf(x1, bx[j][0]);
        float ly = fmaxf(y1, bx[j][1]);
        float rx = fminf(x2, bx[j][2]);
        float ry = fminf(y2, bx[j][3]);
        float iw = fmaxf(rx - lx, 0.0f), ih = fmaxf(ry - ly, 0.0f);
        float inter = iw * ih;
        float a2 = (bx[j][2] - bx[j][0]) * (bx[j][3] - bx[j][1]);
        float uni = fmaxf(a1 + a2 - inter, 1e-7f);
        float iou = inter / uni;   // true IEEE division: matches reference rounding
        if (iou >= 0.5f) m |= 1ull << (j & 63);
      }
    }
    if (i < M) msk[i][w] = m;
  }
  __syncthreads();

  // ---- wave-parallel greedy NMS scan (monotone-ballot) ----
  if (t < 64) {
    u64 kwv[5];
#pragma unroll
    for (int w = 0; w < 5; ++w) {
      const int i = w * 64 + t;
      bool pb = (i < M);
      u64 mown = 0ull;
      if (pb) {
#pragma unroll
        for (int w2 = 0; w2 < 5; ++w2)
          if (w2 < w && (msk[i][w2] & kwv[w2])) pb = false;
        mown = msk[i][w];
      }
      u64 kv = 0ull;
      for (;;) {
        u64 bal = __ballot(pb && ((mown & kv) == 0ull));
        if (!bal) break;
        int p = __ffsll((unsigned long long)bal) - 1;
        kv |= 1ull << p;
        if (t == p) pb = false;
      }
      kwv[w] = kv;
      if (t == 0) keptw[w] = kv;
    }
  }
  __syncthreads();

  for (int i = t; i < M; i += 512) {
    if ((keptw[i >> 6] >> (i & 63)) & 1ull) {
      int rank = 0;
      for (int w = 0; w < (i >> 6); ++w) rank += __popcll(keptw[w]);
      rank += __popcll(keptw[i >> 6] & ((1ull << (i & 63)) - 1ull));
      keptScore[(size_t)bc * KDET + rank] = scl[i];
      keptIdx[(size_t)bc * KDET + rank] = nn_[i];
    }
  }
  if (t == 0) {
    int tot = 0;
    for (int w = 0; w < 5; ++w) tot += __popcll(keptw[w]);
    keptCnt[bc] = (u32)tot;
  }
}

// ---------------- per image: early-term radix top-300 across all classes ----------------
__global__ __launch_bounds__(512) void mergeK(const float* __restrict__ boxes,
                                              const u32* __restrict__ keptCnt,
                                              const float* __restrict__ keptScore,
                                              const u32* __restrict__ keptIdx,
                                              float* __restrict__ out) {
  __shared__ u32 hist[2048];   // 8 KB
  __shared__ int msc[NCLS];
  __shared__ u64 tk[512];
  __shared__ u64 spfx, sand, sor;
  __shared__ u32 sk, ssel, stcnt, smtot;

  const int t = threadIdx.x;
  const int b = blockIdx.x;
  if (t < NCLS) msc[t] = min((int)keptCnt[b * NCLS + t], KDET);
  if (t == 0) {
    spfx = 0ull; sk = KDET; stcnt = 0u; smtot = 0u; sand = ~0ull; sor = 0ull;
  }
  __syncthreads();

  const float* ksc = keptScore + (size_t)b * NCLS * KDET;
  // key reconstruction: (score_bits<<32)|~idx, 0 = invalid
#define MKEY(idx, key) do { \
    int c_ = (idx) / KDET, r_ = (idx) - c_ * KDET; \
    key = (r_ < msc[c_]) ? ((u64)__float_as_uint(ksc[idx]) << 32) | (u32)(~(u32)(idx)) \
                         : 0ull; \
  } while (0)

  {  // AND/OR + total count
    u64 ka = ~0ull, ko = 0ull;
    u32 mycnt = 0;
    for (int idx = t; idx < NCLS * KDET; idx += 512) {
      u64 key; MKEY(idx, key);
      if (key) { ka &= key; ko |= key; ++mycnt; }
    }
#pragma unroll
    for (int off = 32; off > 0; off >>= 1) {
      ka &= __shfl_xor(ka, off);
      ko |= __shfl_xor(ko, off);
      mycnt += __shfl_xor(mycnt, off);
    }
    if ((t & 63) == 0) {
      atomicAnd((unsigned long long*)&sand, (unsigned long long)ka);
      atomicOr((unsigned long long*)&sor, (unsigned long long)ko);
      atomicAdd(&smtot, mycnt);
    }
  }
  __syncthreads();

  const bool mnormal = ((int)smtot > KDET);
  int eshift = 0;
  u64 ethr = 1ull;
  if (mnormal) {
    const u64 kand = sand, kor = sor;
    for (int p = 0; p < 6; ++p) {
      const int nb = (p == 5) ? 512 : 2048;
      const u32 mask = (u32)(nb - 1);
      const u32 ba = (u32)(kand >> RSH[p]) & mask;
      const u32 bo = (u32)(kor >> RSH[p]) & mask;
      if (ba == bo) {
        if (t == 0) spfx = (spfx << RWD[p]) | (u64)ba;
        __syncthreads();
        continue;
      }
      for (int i = t; i < nb; i += 512) hist[i] = 0;
      __syncthreads();
      const u64 pfx = spfx;
      const u32 skPrev = sk;
      for (int idx = t; idx < NCLS * KDET; idx += 512) {
        u64 key; MKEY(idx, key);
        if (!key) continue;
        if (p > 0 && (key >> RSH[p - 1]) != pfx) continue;
        atomicAdd(&hist[(u32)(key >> RSH[p]) & mask], 1u);
      }
      __syncthreads();
      radix_step(hist, nb, RWD[p], &sk, &spfx, &ssel);
      __syncthreads();
      if ((u32)KDET - skPrev + ssel <= 512u) { eshift = RSH[p]; break; }
    }
    ethr = spfx;
  }

  tk[t] = 0ull;
  __syncthreads();
  {
    const int lane = t & 63;
    const u64 lmlt = (1ull << lane) - 1ull;
    for (int i0 = 0; i0 < NCLS * KDET; i0 += 512) {   // uniform trips: safe ballots
      const int idx = i0 + t;
      u64 key = 0ull;
      if (idx < NCLS * KDET) MKEY(idx, key);
      bool q = (key != 0ull) && ((key >> eshift) >= ethr);
      u64 bal = __ballot(q);
      u32 nw = (u32)__popcll(bal);
      if (nw) {
        u32 base = 0;
        if (lane == 0) base = atomicAdd(&stcnt, nw);
        base = __shfl(base, 0);
        if (q) {
          u32 pos = base + (u32)__popcll(bal & lmlt);
          if (pos < 512) tk[pos] = key;
        }
      }
    }
  }
  __syncthreads();
#undef MKEY

  bitonic512(tk, t);

  // outputs: boxes [B,K,4] | scores [B,K] | labels [B,K] (as float)
  if (t < KDET) {
    float* ob = out + ((size_t)b * KDET + t) * 4;
    float* os = out + (size_t)BIMG * KDET * 4;
    float* ol = os + (size_t)BIMG * KDET;
    u64 key = tk[t];
    if (key == 0ull) {
      *(float4*)ob = make_float4(-1.f, -1.f, -1.f, -1.f);
      os[(size_t)b * KDET + t] = -1.f;
      ol[(size_t)b * KDET + t] = -1.f;
    } else {
      u32 fi = ~(u32)key;
      int c = fi / KDET, r = fi - c * KDET;
      u32 n = keptIdx[((size_t)b * NCLS + c) * KDET + r];
      *(float4*)ob = *(const float4*)(boxes + ((size_t)b * NBOX + n) * 4);
      os[(size_t)b * KDET + t] = __uint_as_float((u32)(key >> 32));
      ol[(size_t)b * KDET + t] = (float)c;
    }
  }
}

extern "C" void kernel_launch(void* const* d_in, const int* in_sizes, int n_in,
                              void* d_out, int out_size, void* d_ws, size_t ws_size,
                              hipStream_t stream) {
  const float* boxes = (const float*)d_in[0];
  const float* cls = (const float*)d_in[1];
  float* out = (float*)d_out;
  char* ws = (char*)d_ws;

  u32* pushcnt = (u32*)(ws + OFF_PUSHCNT);
  u64* buf = (u64*)(ws + OFF_BUF);
  u32* keptCnt = (u32*)(ws + OFF_KCNT);
  float* keptScore = (float*)(ws + OFF_KSC);
  u32* keptIdx = (u32*)(ws + OFF_KIDX);

  (void)hipMemsetAsync(ws + OFF_PUSHCNT, 0, ZERO_BYTES, stream);

  histK<<<dim3(245, BIMG), 256, 0, stream>>>(cls, pushcnt, buf);
  nmsK<<<BIMG * NCLS, 512, 0, stream>>>(boxes, cls, pushcnt, buf, keptCnt,
                                        keptScore, keptIdx);
  mergeK<<<BIMG, 512, 0, stream>>>(boxes, keptCnt, keptScore, keptIdx, out);
}

// Round 4
// 520.290 us; speedup vs baseline: 1.0453x; 1.0052x over previous
//
#include <hip/hip_runtime.h>

#define BIMG 8
#define NBOX 100000
#define NCLS 80
#define KDET 300
#define CAP  2048
#define CAPC 12                 // per-block per-class LDS staging capacity
#define TPUSH 0.9921875f        // common-path push threshold (127/128): E[cnt]=781
#define SCORE_T 0.05f
#define NELEM 8000000           // N*C per image
#define NQ    2000000           // float4s per image

typedef unsigned long long u64;
typedef unsigned u32;

// workspace layout (bytes)
#define OFF_PUSHCNT 0u              // 640*4 = 2560
#define ZERO_BYTES  2560u
#define OFF_BUF     4096u           // 640*2048*8 = 10485760
#define OFF_KCNT    (4096u + 10485760u)     // 640*4
#define OFF_KSC     (OFF_KCNT + 2560u)      // 640*300*4
#define OFF_KIDX    (OFF_KSC + 768000u)     // 640*300*4

static __device__ __forceinline__ u64 mk_key(float sc, u32 n) {
  return ((u64)__float_as_uint(sc) << 32) | (u32)(~n);
}

static __device__ __forceinline__ u64 shr64(u64 v, int s) {
  return (s >= 64) ? 0ull : (v >> s);
}

// One radix-select step over hist[2048], executed by wave 0.
// Finds bin of the sk-th largest (from top), spfx = (spfx<<11)|bin, updates sk.
// ssel = #keys in current subset with digit >= chosen bin (for early-exit).
// Caller must __syncthreads() before and after.
static __device__ __forceinline__ void radix_step(const u32* hist, u32* sk,
                                                  u64* spfx, u32* ssel) {
  if (threadIdx.x < 64) {
    const int lane = threadIdx.x;
    const int chunk = 32;                // 2048/64
    u32 psum = 0;
    for (int i = 0; i < chunk; ++i) psum += hist[lane * chunk + i];
    u32 suf = psum;
#pragma unroll
    for (int off = 1; off < 64; off <<= 1) {
      u32 o = __shfl_down(suf, off);
      if (lane + off < 64) suf += o;
    }
    u32 k = *sk;
    u64 bal = __ballot(suf >= k);
    if (bal != 0ull) {
      int L = 63 - __clzll((long long)bal);
      if (lane == L) {
        u32 krem = k - (suf - psum);     // remaining within this chunk (from top)
        int bi = (L + 1) * chunk - 1;
        u32 acc = 0;
        for (;;) {
          acc += hist[bi];
          if (acc >= krem || bi == L * chunk) break;
          --bi;
        }
        *spfx = (*spfx << 11) | (u32)bi;
        *sk = krem - (acc - hist[bi]);
        *ssel = (suf - psum) + acc;      // keys with digit >= bi in subset
      }
    }
  }
}

// ---------------- pass A: threshold push with block-local aggregation ----------------
static __device__ __forceinline__ void pushone(int c, float sc, u32 n, int b,
                                               u32* lcnt, u64* stage,
                                               u32* pushcnt, u64* buf) {
  u64 key = mk_key(sc, n);
  u32 slot = atomicAdd(&lcnt[c], 1u);
  if (slot < CAPC) {
    stage[c * CAPC + slot] = key;
  } else {    // rare LDS-staging overflow: direct global push
    u32 g = atomicAdd(&pushcnt[b * NCLS + c], 1u);
    if (g < CAP) buf[(size_t)(b * NCLS + c) * CAP + g] = key;
  }
}

__global__ __launch_bounds__(256) void histK(const float* __restrict__ cls,
                                             u32* __restrict__ pushcnt,
                                             u64* __restrict__ buf) {
  __shared__ u32 lcnt[NCLS];
  __shared__ u32 sbase[NCLS];
  __shared__ u64 stage[NCLS * CAPC];   // 7.7 KB

  const int t = threadIdx.x;
  const int b = blockIdx.y;
  for (int i = t; i < NCLS; i += 256) lcnt[i] = 0;
  __syncthreads();

  const float4* base4 = (const float4*)(cls + (size_t)b * NELEM);
  const int start = blockIdx.x * 8192;   // 245 blocks/img * 8192 float4 >= 2M

#define PROCQ(u) do { \
    float mx = fmaxf(fmaxf(v##u.x, v##u.y), fmaxf(v##u.z, v##u.w)); \
    if (mx >= TPUSH) { \
      const int e0 = q##u * 4; \
      const int c0 = e0 % NCLS; \
      const u32 n = (u32)(e0 / NCLS); \
      if (v##u.x >= TPUSH) pushone(c0 + 0, v##u.x, n, b, lcnt, stage, pushcnt, buf); \
      if (v##u.y >= TPUSH) pushone(c0 + 1, v##u.y, n, b, lcnt, stage, pushcnt, buf); \
      if (v##u.z >= TPUSH) pushone(c0 + 2, v##u.z, n, b, lcnt, stage, pushcnt, buf); \
      if (v##u.w >= TPUSH) pushone(c0 + 3, v##u.w, n, b, lcnt, stage, pushcnt, buf); \
    } } while (0)

  if (start + 8192 <= NQ) {            // full blocks: no bounds checks
    for (int it = 0; it < 4; ++it) {
      const int qb = start + it * 2048 + t;
#define LOADF(u) const int q##u = qb + (u) * 256; const float4 v##u = base4[q##u]
      LOADF(0); LOADF(1); LOADF(2); LOADF(3);
      LOADF(4); LOADF(5); LOADF(6); LOADF(7);
#undef LOADF
      PROCQ(0); PROCQ(1); PROCQ(2); PROCQ(3);
      PROCQ(4); PROCQ(5); PROCQ(6); PROCQ(7);
    }
  } else {                              // tail block: checked loads
    for (int it = 0; it < 4; ++it) {
      const int qb = start + it * 2048 + t;
#define LOADC(u) const int q##u = qb + (u) * 256; \
  const float4 v##u = (q##u < NQ) ? base4[q##u] : make_float4(0.f, 0.f, 0.f, 0.f)
      LOADC(0); LOADC(1); LOADC(2); LOADC(3);
      LOADC(4); LOADC(5); LOADC(6); LOADC(7);
#undef LOADC
      PROCQ(0); PROCQ(1); PROCQ(2); PROCQ(3);
      PROCQ(4); PROCQ(5); PROCQ(6); PROCQ(7);
    }
  }
#undef PROCQ
  __syncthreads();

  // one global atomic per (block, class) to reserve a contiguous range
  if (t < NCLS) {
    u32 cnt = min(lcnt[t], (u32)CAPC);
    sbase[t] = cnt ? atomicAdd(&pushcnt[b * NCLS + t], cnt) : 0u;
  }
  __syncthreads();
  for (int idx = t; idx < NCLS * CAPC; idx += 256) {
    const int c = idx / CAPC;
    const int k = idx - c * CAPC;
    if ((u32)k < min(lcnt[c], (u32)CAPC)) {
      u32 s = sbase[c] + (u32)k;
      if (s < CAP) buf[(size_t)(b * NCLS + c) * CAP + s] = stage[idx];
    }
  }
}

// ---------------- per (b,c): fallback (fused, rare) + 1-pass dynamic radix select
// + rank-sort + NMS + compact ----------------
__global__ __launch_bounds__(512) void nmsK(const float* __restrict__ boxes,
                                            const float* __restrict__ cls,
                                            const u32* __restrict__ pushcnt,
                                            u64* __restrict__ buf,
                                            u32* __restrict__ keptCnt,
                                            float* __restrict__ keptScore,
                                            u32* __restrict__ keptIdx) {
  __shared__ float bx[KDET][5];                 // 6 KB (stride-5: bank-spread)
  __shared__ float scl[KDET];
  __shared__ u32 nn_[KDET];
  __shared__ u64 msk[KDET][5];                  // 12 KB (aliased as hist scratch)
  __shared__ u64 tk[512];                       // 4 KB
  __shared__ u64 keptw[5];
  __shared__ u64 spfx;
  __shared__ u64 sand, sor;
  __shared__ u32 sk, ssel, stcnt;
  __shared__ u32 sfpfx, sfk, sfab, sfeq, sfmode, sfbcnt;

  const int t = threadIdx.x;
  const int bc = blockIdx.x;
  const int b = bc / NCLS;
  u64* bufp = buf + (size_t)bc * CAP;
  u32* hist = (u32*)&msk[0][0];   // 2048-bin scratch, dead before masks are built

  if (t == 0) { spfx = 0ull; sk = KDET; stcnt = 0u; sfmode = 0u; sfbcnt = 0u; }

  // ---- fused exact fallback (never taken on common inputs) ----
  u32 realcnt = pushcnt[bc];
  const bool dofb = !(realcnt >= (u32)KDET && realcnt <= (u32)CAP);
  if (dofb) {
    const int c = bc % NCLS;
    const float* col = cls + (size_t)b * NELEM + c;
    // MSD radix-select of the 300th-largest score-bits
    for (int r = 0; r < 3; ++r) {
      const int shift = (r == 0) ? 21 : (r == 1) ? 10 : 0;
      const int nbins = (r == 2) ? 1024 : 2048;
      for (int i = t; i < nbins; i += 512) hist[i] = 0;
      __syncthreads();
      for (int n = t; n < NBOX; n += 512) {
        float sc = col[(size_t)n * NCLS];
        if (sc > SCORE_T) {
          u32 u = __float_as_uint(sc);
          bool ok = (r == 0) || (r == 1 ? ((u >> 21) == (sfpfx >> 21))
                                        : ((u >> 10) == (sfpfx >> 10)));
          if (ok) atomicAdd(&hist[(u >> shift) & (u32)(nbins - 1)], 1u);
        }
      }
      __syncthreads();
      if (t == 0) {
        if (r == 0) {
          u32 s = 0;
          for (int i = 0; i < nbins; ++i) s += hist[i];
          if (s < KDET) sfmode = 1u;   // fewer than 300 candidates: push all
        }
        if (sfmode == 0u) {
          u32 kk2 = (r == 0) ? (u32)KDET : sfk;
          u32 acc = 0;
          int bi = nbins - 1;
          for (; bi >= 0; --bi) {
            if (acc + hist[bi] >= kk2) break;
            acc += hist[bi];
          }
          sfk = kk2 - acc;
          sfpfx = ((r == 0) ? 0u : sfpfx) | ((u32)bi << shift);
          if (r == 2) { sfeq = hist[bi]; sfab = KDET - sfk; }
        }
      }
      __syncthreads();
      if (sfmode == 1u) break;
    }

    if (sfmode == 1u) {
      for (int n = t; n < NBOX; n += 512) {
        float sc = col[(size_t)n * NCLS];
        if (sc > SCORE_T) {
          u32 g = atomicAdd(&sfbcnt, 1u);
          if (g < CAP) bufp[g] = mk_key(sc, (u32)n);
        }
      }
    } else {
      const u32 ustar = sfpfx;
      const u32 m = sfab, e = sfeq;
      if (m + e <= CAP) {
        for (int n = t; n < NBOX; n += 512) {
          float sc = col[(size_t)n * NCLS];
          if (sc > SCORE_T && __float_as_uint(sc) >= ustar) {
            u32 g = atomicAdd(&sfbcnt, 1u);
            if (g < CAP) bufp[g] = mk_key(sc, (u32)n);
          }
        }
      } else {
        for (int n = t; n < NBOX; n += 512) {
          float sc = col[(size_t)n * NCLS];
          if (sc > SCORE_T && __float_as_uint(sc) > ustar) {
            u32 g = atomicAdd(&sfbcnt, 1u);
            if (g < CAP) bufp[g] = mk_key(sc, (u32)n);
          }
        }
        __syncthreads();
        if (t == 0) {
          u32 room = CAP - m, got = 0;
          for (int n = 0; n < NBOX && got < room; ++n) {
            float sc = col[(size_t)n * NCLS];
            if (sc > SCORE_T && __float_as_uint(sc) == ustar) {
              u32 g = atomicAdd(&sfbcnt, 1u);
              if (g < CAP) bufp[g] = mk_key(sc, (u32)n);
              ++got;
            }
          }
        }
      }
    }
    __threadfence_block();
    __syncthreads();
    realcnt = sfbcnt;
  }
  const int cnt = min((int)realcnt, CAP);

  u64 kk[4];
#pragma unroll
  for (int u = 0; u < 4; ++u) {
    int i = t + u * 512;
    u64 v = 0ull;
    if (i < cnt)
      v = dofb ? *((volatile const u64*)(bufp + i)) : bufp[i];   // L1-bypass on rare path
    kk[u] = v;
  }

  const bool normal = (cnt > KDET);   // block-uniform
  int eshift = 0;
  u64 ethr = 1ull;                    // !normal: take every nonzero key
  if (normal) {
    // block AND/OR of keys -> highest varying bit anchors the radix window
    if (t == 0) { sand = ~0ull; sor = 0ull; }
    __syncthreads();
    {
      u64 ka = ~0ull, ko = 0ull;
#pragma unroll
      for (int u = 0; u < 4; ++u) {
        u64 key = kk[u];
        if (key) { ka &= key; ko |= key; }
      }
#pragma unroll
      for (int off = 32; off > 0; off >>= 1) {
        ka &= __shfl_xor(ka, off);
        ko |= __shfl_xor(ko, off);
      }
      if ((t & 63) == 0) {
        atomicAnd((unsigned long long*)&sand, (unsigned long long)ka);
        atomicOr((unsigned long long*)&sor, (unsigned long long)ko);
      }
    }
    __syncthreads();
    const u64 kand = sand, kor = sor;
    const u64 W = kand ^ kor;        // != 0: >=301 distinct keys
    const int hv = 63 - __clzll((long long)W);
    int s = 11 * (hv / 11);          // windows tile [s, s+10], stepping by 11 to 0
    if (t == 0) spfx = shr64(kand, s + 11);   // constant high bits seed the prefix
    for (;;) {
      for (int i = t; i < 2048; i += 512) hist[i] = 0;
      __syncthreads();
      const u64 pfxHi = spfx;        // threshold value at granularity s+11
      const u32 skPrev = sk;
#pragma unroll
      for (int u = 0; u < 4; ++u) {
        u64 key = kk[u];
        if (!key) continue;
        if (shr64(key, s + 11) != pfxHi) continue;
        atomicAdd(&hist[(u32)(key >> s) & 2047u], 1u);
      }
      __syncthreads();
      radix_step(hist, &sk, &spfx, &ssel);
      __syncthreads();
      // keys >= (prefix|bin) = taken-above-subset + (digit >= bin within subset)
      if ((u32)KDET - skPrev + ssel <= 512u || s == 0) { eshift = s; break; }
      s -= 11;
    }
    ethr = spfx;   // threshold at granularity eshift; superset fits 512
  } else {
    __syncthreads();
  }

  tk[t] = 0ull;
  __syncthreads();
  {
    const int lane = t & 63;
    const u64 lmlt = (1ull << lane) - 1ull;
#pragma unroll
    for (int u = 0; u < 4; ++u) {
      u64 key = kk[u];
      bool q = (key != 0ull) && (shr64(key, eshift) >= ethr);
      u64 bal = __ballot(q);
      u32 nw = (u32)__popcll(bal);
      if (nw) {
        u32 base = 0;
        if (lane == 0) base = atomicAdd(&stcnt, nw);
        base = __shfl(base, 0);
        if (q) {
          u32 pos = base + (u32)__popcll(bal & lmlt);
          if (pos < 512) tk[pos] = key;
        }
      }
    }
  }
  __syncthreads();

  // ---- rank-by-counting sort fused with box gather ----
  // tk[0..sc) hold the selected keys contiguously (unique). rank via LDS
  // broadcast reads; each thread scatters its box/score/idx to sorted slot.
  const int sc = min((int)stcnt, 512);
  const int M = min(sc, KDET);
  {
    const u64 mykey = tk[t];
    const int scU = (sc + 7) & ~7;     // tk pre-zeroed: padding reads compare false
    int rank = 0;
    for (int j = 0; j < scU; j += 8) {
#pragma unroll
      for (int jj = 0; jj < 8; ++jj) rank += (tk[j + jj] > mykey) ? 1 : 0;
    }
    if (mykey != 0ull && rank < KDET) {
      u32 n = ~(u32)mykey;
      scl[rank] = __uint_as_float((u32)(mykey >> 32));
      nn_[rank] = n;
      const float4 bv = *(const float4*)(boxes + ((size_t)b * NBOX + n) * 4);
      bx[rank][0] = bv.x; bx[rank][1] = bv.y; bx[rank][2] = bv.z; bx[rank][3] = bv.w;
    }
  }
  __syncthreads();

  // suppression masks, task-split: task = (row i, 64-col word w), 1500 tasks
  for (int tau = t; tau < KDET * 5; tau += 512) {
    const int i = tau / 5;
    const int w = tau - i * 5;
    u64 m = 0ull;
    const int jb = w << 6;
    if (i < M && jb < i) {
      const int je = min(i, jb + 64);
      const float x1 = bx[i][0], y1 = bx[i][1], x2 = bx[i][2], y2 = bx[i][3];
      const float a1 = (x2 - x1) * (y2 - y1);
      for (int j = jb; j < je; ++j) {
        float lx = fmaxf(x1, bx[j][0]);
        float ly = fmaxf(y1, bx[j][1]);
        float rx = fminf(x2, bx[j][2]);
        float ry = fminf(y2, bx[j][3]);
        float iw = fmaxf(rx - lx, 0.0f), ih = fmaxf(ry - ly, 0.0f);
        float inter = iw * ih;
        float a2 = (bx[j][2] - bx[j][0]) * (bx[j][3] - bx[j][1]);
        float uni = fmaxf(a1 + a2 - inter, 1e-7f);
        float iou = inter / uni;   // true IEEE division: matches reference rounding
        if (iou >= 0.5f) m |= 1ull << (j & 63);
      }
    }
    if (i < M) msk[i][w] = m;
  }
  __syncthreads();

  // ---- wave-parallel greedy NMS scan (monotone-ballot) ----
  if (t < 64) {
    u64 kwv[5];
#pragma unroll
    for (int w = 0; w < 5; ++w) {
      const int i = w * 64 + t;
      bool pb = (i < M);
      u64 mown = 0ull;
      if (pb) {
#pragma unroll
        for (int w2 = 0; w2 < 5; ++w2)
          if (w2 < w && (msk[i][w2] & kwv[w2])) pb = false;
        mown = msk[i][w];
      }
      u64 kv = 0ull;
      for (;;) {
        u64 bal = __ballot(pb && ((mown & kv) == 0ull));
        if (!bal) break;
        int p = __ffsll((unsigned long long)bal) - 1;
        kv |= 1ull << p;
        if (t == p) pb = false;
      }
      kwv[w] = kv;
      if (t == 0) keptw[w] = kv;
    }
  }
  __syncthreads();

  for (int i = t; i < M; i += 512) {
    if ((keptw[i >> 6] >> (i & 63)) & 1ull) {
      int rank = 0;
      for (int w = 0; w < (i >> 6); ++w) rank += __popcll(keptw[w]);
      rank += __popcll(keptw[i >> 6] & ((1ull << (i & 63)) - 1ull));
      keptScore[(size_t)bc * KDET + rank] = scl[i];
      keptIdx[(size_t)bc * KDET + rank] = nn_[i];
    }
  }
  if (t == 0) {
    int tot = 0;
    for (int w = 0; w < 5; ++w) tot += __popcll(keptw[w]);
    keptCnt[bc] = (u32)tot;
  }
}

// ---------------- per image: dynamic radix top-300 across all classes ----------------
__global__ __launch_bounds__(512) void mergeK(const float* __restrict__ boxes,
                                              const u32* __restrict__ keptCnt,
                                              const float* __restrict__ keptScore,
                                              const u32* __restrict__ keptIdx,
                                              float* __restrict__ out) {
  __shared__ u32 hist[2048];   // 8 KB
  __shared__ int msc[NCLS];
  __shared__ u64 tk[512];
  __shared__ u64 spfx, sand, sor;
  __shared__ u32 sk, ssel, stcnt, smtot;

  const int t = threadIdx.x;
  const int b = blockIdx.x;
  if (t < NCLS) msc[t] = min((int)keptCnt[b * NCLS + t], KDET);
  if (t == 0) {
    spfx = 0ull; sk = KDET; stcnt = 0u; smtot = 0u; sand = ~0ull; sor = 0ull;
  }
  __syncthreads();

  const float* ksc = keptScore + (size_t)b * NCLS * KDET;
  // key reconstruction: (score_bits<<32)|~idx, 0 = invalid
#define MKEY(idx, key) do { \
    int c_ = (idx) / KDET, r_ = (idx) - c_ * KDET; \
    key = (r_ < msc[c_]) ? ((u64)__float_as_uint(ksc[idx]) << 32) | (u32)(~(u32)(idx)) \
                         : 0ull; \
  } while (0)

  {  // AND/OR + total count
    u64 ka = ~0ull, ko = 0ull;
    u32 mycnt = 0;
    for (int idx = t; idx < NCLS * KDET; idx += 512) {
      u64 key; MKEY(idx, key);
      if (key) { ka &= key; ko |= key; ++mycnt; }
    }
#pragma unroll
    for (int off = 32; off > 0; off >>= 1) {
      ka &= __shfl_xor(ka, off);
      ko |= __shfl_xor(ko, off);
      mycnt += __shfl_xor(mycnt, off);
    }
    if ((t & 63) == 0) {
      atomicAnd((unsigned long long*)&sand, (unsigned long long)ka);
      atomicOr((unsigned long long*)&sor, (unsigned long long)ko);
      atomicAdd(&smtot, mycnt);
    }
  }
  __syncthreads();

  const bool mnormal = ((int)smtot > KDET);
  int eshift = 0;
  u64 ethr = 1ull;
  if (mnormal) {
    const u64 kand = sand, kor = sor;
    const u64 W = kand ^ kor;
    const int hv = 63 - __clzll((long long)W);
    int s = 11 * (hv / 11);
    if (t == 0) spfx = shr64(kand, s + 11);
    for (;;) {
      for (int i = t; i < 2048; i += 512) hist[i] = 0;
      __syncthreads();
      const u64 pfxHi = spfx;
      const u32 skPrev = sk;
      for (int idx = t; idx < NCLS * KDET; idx += 512) {
        u64 key; MKEY(idx, key);
        if (!key) continue;
        if (shr64(key, s + 11) != pfxHi) continue;
        atomicAdd(&hist[(u32)(key >> s) & 2047u], 1u);
      }
      __syncthreads();
      radix_step(hist, &sk, &spfx, &ssel);
      __syncthreads();
      if ((u32)KDET - skPrev + ssel <= 512u || s == 0) { eshift = s; break; }
      s -= 11;
    }
    ethr = spfx;
  }

  tk[t] = 0ull;
  __syncthreads();
  {
    const int lane = t & 63;
    const u64 lmlt = (1ull << lane) - 1ull;
    for (int i0 = 0; i0 < NCLS * KDET; i0 += 512) {   // uniform trips: safe ballots
      const int idx = i0 + t;
      u64 key = 0ull;
      if (idx < NCLS * KDET) MKEY(idx, key);
      bool q = (key != 0ull) && (shr64(key, eshift) >= ethr);
      u64 bal = __ballot(q);
      u32 nw = (u32)__popcll(bal);
      if (nw) {
        u32 base = 0;
        if (lane == 0) base = atomicAdd(&stcnt, nw);
        base = __shfl(base, 0);
        if (q) {
          u32 pos = base + (u32)__popcll(bal & lmlt);
          if (pos < 512) tk[pos] = key;
        }
      }
    }
  }
  __syncthreads();
#undef MKEY

  // ---- rank-by-counting sort: tk -> sorted tk ----
  const int sc = min((int)stcnt, 512);
  {
    const u64 mykey = tk[t];
    const int scU = (sc + 7) & ~7;
    int rank = 0;
    for (int j = 0; j < scU; j += 8) {
#pragma unroll
      for (int jj = 0; jj < 8; ++jj) rank += (tk[j + jj] > mykey) ? 1 : 0;
    }
    __syncthreads();               // all rank reads done before overwrite
    tk[t] = 0ull;
    __syncthreads();
    if (mykey != 0ull && rank < KDET) tk[rank] = mykey;
  }
  __syncthreads();

  // outputs: boxes [B,K,4] | scores [B,K] | labels [B,K] (as float)
  if (t < KDET) {
    float* ob = out + ((size_t)b * KDET + t) * 4;
    float* os = out + (size_t)BIMG * KDET * 4;
    float* ol = os + (size_t)BIMG * KDET;
    u64 key = tk[t];
    if (key == 0ull) {
      *(float4*)ob = make_float4(-1.f, -1.f, -1.f, -1.f);
      os[(size_t)b * KDET + t] = -1.f;
      ol[(size_t)b * KDET + t] = -1.f;
    } else {
      u32 fi = ~(u32)key;
      int c = fi / KDET, r = fi - c * KDET;
      u32 n = keptIdx[((size_t)b * NCLS + c) * KDET + r];
      *(float4*)ob = *(const float4*)(boxes + ((size_t)b * NBOX + n) * 4);
      os[(size_t)b * KDET + t] = __uint_as_float((u32)(key >> 32));
      ol[(size_t)b * KDET + t] = (float)c;
    }
  }
}

extern "C" void kernel_launch(void* const* d_in, const int* in_sizes, int n_in,
                              void* d_out, int out_size, void* d_ws, size_t ws_size,
                              hipStream_t stream) {
  const float* boxes = (const float*)d_in[0];
  const float* cls = (const float*)d_in[1];
  float* out = (float*)d_out;
  char* ws = (char*)d_ws;

  u32* pushcnt = (u32*)(ws + OFF_PUSHCNT);
  u64* buf = (u64*)(ws + OFF_BUF);
  u32* keptCnt = (u32*)(ws + OFF_KCNT);
  float* keptScore = (float*)(ws + OFF_KSC);
  u32* keptIdx = (u32*)(ws + OFF_KIDX);

  (void)hipMemsetAsync(ws + OFF_PUSHCNT, 0, ZERO_BYTES, stream);

  histK<<<dim3(245, BIMG), 256, 0, stream>>>(cls, pushcnt, buf);
  nmsK<<<BIMG * NCLS, 512, 0, stream>>>(boxes, cls, pushcnt, buf, keptCnt,
                                        keptScore, keptIdx);
  mergeK<<<BIMG, 512, 0, stream>>>(boxes, keptCnt, keptScore, keptIdx, out);
}